// Round 21
// baseline (69.800 us; speedup 1.0000x reference)
//
#include <hip/hip_runtime.h>

#define NW 3
#define NF 48
#define NHOST 16
#define NLAT 10
#define GOUT 16
#define EDIM 19
#define PDIM 10

// const-buffer layout (floats)
#define CB_M    0     // 19x19  Wq^T Wk
#define CB_P    361   // 19x19  Wout Wv
#define CB_G    722   // 19     bq^T Wk
#define CB_H    741   // 19     Wq^T bk
#define CB_R    760   // 19     Wout bv + bout
#define CB_C0   779   // 1      bq.bk
#define CB_WAL  780   // 3      gatW @ gal
#define CB_WAR  783   // 3      gatW @ gar
#define CB_CBIG 800   // 176    folded head biases
#define CB_BF   976   // 11264 ushorts: B-frags of Wbig^T, bf16
#define CB_TOT  10240

typedef __attribute__((ext_vector_type(8))) short bf16x8;
typedef __attribute__((ext_vector_type(4))) float f32x4;

__device__ __forceinline__ float frcp(float x){ return __builtin_amdgcn_rcpf(x); }
__device__ __forceinline__ float fsig(float x){ return frcp(1.f + __expf(-x)); }
__device__ __forceinline__ float ftanh(float x){ return 1.f - 2.f*frcp(1.f + __expf(2.f*x)); }
__device__ __forceinline__ unsigned short f2bf(float x){
    union { float f; unsigned u; } v; v.f = x;
    unsigned r = v.u + 0x7FFFu + ((v.u >> 16) & 1u);
    return (unsigned short)(r >> 16);
}

// ---------------- K0: fold weights; grid-parallel ----------------
__global__ __launch_bounds__(256) void k_const(
    const float* __restrict__ Win, const float* __restrict__ bin,
    const float* __restrict__ Wout, const float* __restrict__ bout,
    const float* __restrict__ gatW, const float* __restrict__ gal,
    const float* __restrict__ gar, const float* __restrict__ encW,
    const float* __restrict__ encb,
    const float* __restrict__ aW, const float* __restrict__ ab,
    const float* __restrict__ pW, const float* __restrict__ pb,
    float* __restrict__ cb)
{
    const int w = blockIdx.x*blockDim.x + threadIdx.x;
    if (w < 786) {
        const int idx = w;
        float acc = 0.f;
        if (idx < 361) {
            int i = idx/19, j = idx%19;
            for (int e = 0; e < EDIM; ++e) acc += Win[e*EDIM+i]*Win[(EDIM+e)*EDIM+j];
        } else if (idx < 722) {
            int k = idx-361; int i = k/19, j = k%19;
            for (int e = 0; e < EDIM; ++e) acc += Wout[i*EDIM+e]*Win[(2*EDIM+e)*EDIM+j];
        } else if (idx < 741) {
            int j = idx-722;
            for (int e = 0; e < EDIM; ++e) acc += bin[e]*Win[(EDIM+e)*EDIM+j];
        } else if (idx < 760) {
            int i = idx-741;
            for (int e = 0; e < EDIM; ++e) acc += Win[e*EDIM+i]*bin[EDIM+e];
        } else if (idx < 779) {
            int i = idx-760; acc = bout[i];
            for (int e = 0; e < EDIM; ++e) acc += Wout[i*EDIM+e]*bin[2*EDIM+e];
        } else if (idx == 779) {
            for (int e = 0; e < EDIM; ++e) acc += bin[e]*bin[EDIM+e];
        } else {
            int c = idx-780; int cc = c%3; bool left = c<3;
            for (int f2 = 0; f2 < GOUT; ++f2)
                acc += gatW[cc*GOUT+f2]*(left ? gal[f2] : gar[f2]);
        }
        cb[idx] = acc;
    } else if (w < 962) {
        const int g = w - 786;
        int host = g / 11, jj = g % 11;
        float acc = (jj == 0) ? (ab[0] - ab[1]) : pb[jj-1];
        for (int l = 0; l < NLAT; ++l) {
            float coef = (jj == 0) ? (aW[l] - aW[NLAT+l]) : pW[(jj-1)*NLAT + l];
            acc += coef * encb[host*NLAT + l];
        }
        cb[CB_CBIG + g] = acc;
    } else if (w < 12226) {
        unsigned short* bf = (unsigned short*)(cb + CB_BF);
        const int u = w - 962;
        int j    = u & 7;
        int lane = (u >> 3) & 63;
        int tile = u >> 9;
        int half = tile / 11, n = tile % 11;
        int k = half*32 + ((lane >> 4) & 3)*8 + j;
        int g = n*16 + (lane & 15);
        float acc = 0.f;
        if (k < 57) {
            int host = g / 11, jj = g % 11;
            for (int l = 0; l < NLAT; ++l) {
                float coef = (jj == 0) ? (aW[l] - aW[NLAT+l]) : pW[(jj-1)*NLAT + l];
                acc += coef * encW[(host*NLAT + l)*57 + k];
            }
        }
        bf[u] = f2bf(acc);
    }
}

// ---------------- K1: fused F+M+E, 1-wave block per 16-b tile ----------------
// R21: coalesced t staging (F0). R20's lane=(bl,w) t reads had a 576B lane
// stride (uncoalesced, ~48 lines/wave-load) -> F0 stages the tile's 576
// float4s with the lane+64r pattern (1KB/instr) into xs2[48][52] f32;
// F reads x from LDS. pcb now has its own region (one barrier fewer).
__global__ __launch_bounds__(64, 4) void k_fused(
    const float* __restrict__ t, const float* __restrict__ h0,
    const float* __restrict__ Wih, const float* __restrict__ bih,
    const float* __restrict__ gatW, const float* __restrict__ Whh,
    const float* __restrict__ bhh, const float* __restrict__ cb,
    float* __restrict__ outA, float* __restrict__ outP, int B)
{
    __shared__ __align__(16) char smraw[14784];
    __shared__ __align__(16) unsigned short a2[16][64];            // 2048B
    float (*fm)[25][16]    = reinterpret_cast<float(*)[25][16]>(smraw);             // 4800B
    float (*xs2)[52]       = reinterpret_cast<float(*)[52]>(smraw + 4800);          // 9984B (F only)
    float (*mtb)[EDIM][16] = reinterpret_cast<float(*)[EDIM][16]>(smraw + 4800);    // 3648B (alias xs2)
    float (*gtb)[16]       = reinterpret_cast<float(*)[16]>(smraw + 4800 + 3648);   // 192B
    float (*pcb)[EDIM][16] = reinterpret_cast<float(*)[EDIM][16]>(smraw + 4800 + 3840); // 3648B (own)
    _Float16 (*lg)[178]    = reinterpret_cast<_Float16(*)[178]>(smraw);             // 5696B (E)

    const int lane = threadIdx.x;
    const int b0   = blockIdx.x * 16;
    const int bl   = lane & 15;
    const int sw   = lane >> 4;          // 0..3

    // ======== F0: coalesced t staging (all 64 lanes) ========
    {
        const float4* tq = reinterpret_cast<const float4*>(t + (size_t)b0*NW*NF);
#pragma unroll
        for (int r = 0; r < 9; ++r) {
            const int f = lane + 64*r;           // 0..575
            float4 v = tq[f];
            const int b_   = f / 36;             // 36 float4 per b
            const int off4 = f - b_*36;
            const int w_   = off4 / 12, j4 = off4 - w_*12;
            *reinterpret_cast<float4*>(&xs2[b_*3 + w_][j4*4]) = v;
        }
    }
    __syncthreads();                                     // B0 (xs2 ready)

    // ================= phase F (lanes 0-47: (bl, w=sw)) =================
    if (lane < 48) {
        const float* xrow = xs2[bl*3 + sw];

        const float Wal0=cb[CB_WAL],Wal1=cb[CB_WAL+1],Wal2=cb[CB_WAL+2];
        const float War0=cb[CB_WAR],War1=cb[CB_WAR+1],War2=cb[CB_WAR+2];

        float gi[9];
#pragma unroll
        for (int r = 0; r < 9; ++r) gi[r] = bih[r];
        float el[NHOST], er[NHOST];
#pragma unroll
        for (int c = 0; c < 4; ++c) {
            float xc[12];
#pragma unroll
            for (int k = 0; k < 12; ++k) xc[k] = xrow[c*12 + k];
#pragma unroll
            for (int r = 0; r < 9; ++r) {
                float a = 0.f;
#pragma unroll
                for (int k = 0; k < 12; ++k) a += xc[k]*Wih[r*NF + c*12 + k];
                gi[r] += a;
            }
#pragma unroll
            for (int u = 0; u < 4; ++u) {
                const int uu = c*4 + u;
                el[uu] = xc[u*3]*Wal0 + xc[u*3+1]*Wal1 + xc[u*3+2]*Wal2;
                er[uu] = xc[u*3]*War0 + xc[u*3+1]*War1 + xc[u*3+2]*War2;
            }
        }
        const int w = sw;
#pragma unroll
        for (int r = 0; r < 9; ++r) fm[w][r][bl] = gi[r];

        float beta[NHOST];
#pragma unroll
        for (int u = 0; u < NHOST; ++u) beta[u] = 0.f;
#pragma unroll
        for (int v = 0; v < NHOST; ++v) {
            float ee[NHOST]; float sum = 0.f;
#pragma unroll
            for (int u = 0; u < NHOST; ++u) {
                float s = er[v] + el[u];
                s = fmaxf(s, 0.2f*s);
                ee[u] = __expf(s); sum += ee[u];
            }
            float inv = frcp(sum);
#pragma unroll
            for (int u = 0; u < NHOST; ++u) beta[u] += ee[u]*inv;
        }
        float g0=0.f, g1=0.f, g2=0.f;
#pragma unroll
        for (int u = 0; u < NHOST; ++u) {
            float bu = beta[u]*(1.f/16.f);
            g0 += bu*xrow[u*3+0]; g1 += bu*xrow[u*3+1]; g2 += bu*xrow[u*3+2];
        }
#pragma unroll
        for (int f2 = 0; f2 < GOUT; ++f2)
            fm[w][9+f2][bl] = g0*gatW[f2] + g1*gatW[GOUT+f2] + g2*gatW[2*GOUT+f2];
    }
    __syncthreads();                                     // B1 (fm ready; xs2 dead)

    // ================= phase M (lanes 0-47: (bl, s=sw)) =================
    float cw[EDIM];
    float hsv = 0.f, aw0 = 0.f, aw1 = 0.f, aw2 = 0.f;
#pragma unroll
    for (int i = 0; i < EDIM; ++i) cw[i] = 0.f;

    if (lane < 48) {
        const int s = sw;
        const int b = b0 + bl;
        float h[3] = { h0[(size_t)b*3+0], h0[(size_t)b*3+1], h0[(size_t)b*3+2] };
        float ch[NW][3];
#pragma unroll
        for (int w = 0; w < NW; ++w) {
            float gi[9];
#pragma unroll
            for (int r = 0; r < 9; ++r) gi[r] = fm[w][r][bl];
            float gh[9];
#pragma unroll
            for (int r = 0; r < 9; ++r)
                gh[r] = bhh[r] + h[0]*Whh[r*3+0] + h[1]*Whh[r*3+1] + h[2]*Whh[r*3+2];
#pragma unroll
            for (int j = 0; j < 3; ++j) {
                float rg = fsig(gi[j]   + gh[j]);
                float zg = fsig(gi[3+j] + gh[3+j]);
                float ng = ftanh(gi[6+j] + rg*gh[6+j]);
                h[j] = (1.f - zg)*ng + zg*h[j];
            }
            ch[w][0]=h[0]; ch[w][1]=h[1]; ch[w][2]=h[2];
        }
#pragma unroll
        for (int j = 0; j < 3; ++j)
            cw[j] = (s==0) ? ch[0][j] : (s==1) ? ch[1][j] : ch[2][j];
#pragma unroll
        for (int f2 = 0; f2 < GOUT; ++f2)
            cw[3+f2] = fm[s][9+f2][bl];

        float gt = 0.f;
#pragma unroll
        for (int i = 0; i < EDIM; ++i) { hsv += cw[i]*cb[CB_H+i]; gt += cw[i]*cb[CB_G+i]; }
#pragma unroll
        for (int i = 0; i < EDIM; ++i) {
            float a = 0.f;
#pragma unroll
            for (int j = 0; j < EDIM; ++j) a += cb[CB_M+i*EDIM+j]*cw[j];
            mtb[s][i][bl] = a;                      // mtb aliases xs2 (dead after B1)
        }
        gtb[s][bl] = gt;
    }
    __syncthreads();                                     // B2 (mtb/gtb ready)

    if (lane < 48) {
        const int s = sw;
        const float c0 = cb[CB_C0];
        float sc[NW];
#pragma unroll
        for (int tt = 0; tt < NW; ++tt) {
            float a = 0.f;
#pragma unroll
            for (int i = 0; i < EDIM; ++i) a += cw[i]*mtb[tt][i][bl];
            sc[tt] = (a + gtb[tt][bl] + hsv + c0) * 0.2294157338705618f;
        }
        float m = fmaxf(sc[0], fmaxf(sc[1], sc[2]));
        float e0=__expf(sc[0]-m), e1=__expf(sc[1]-m), e2=__expf(sc[2]-m);
        float inv = frcp(e0+e1+e2);
        aw0=e0*inv; aw1=e1*inv; aw2=e2*inv;

#pragma unroll
        for (int i = 0; i < EDIM; ++i) {
            float a = 0.f;
#pragma unroll
            for (int j = 0; j < EDIM; ++j) a += cb[CB_P+i*EDIM+j]*cw[j];
            pcb[s][i][bl] = a;                      // own region: no extra barrier
        }
    }
    __syncthreads();                                     // B3 (pcb ready)

    if (lane < 48) {
        const int s = sw;
        char* a2c = (char*)a2;
        const int swz = (bl & 7) << 4;
#pragma unroll
        for (int i = 0; i < EDIM; ++i) {
            float v = cb[CB_R+i] + aw0*pcb[0][i][bl] + aw1*pcb[1][i][bl]
                    + aw2*pcb[2][i][bl];
            const int byte = bl*128 + (s*EDIM + i)*2;
            *reinterpret_cast<unsigned short*>(a2c + (byte ^ swz)) = f2bf(v);
        }
        if (s == 0) {
#pragma unroll
            for (int r = 0; r < 7; ++r) {
                const int byte = bl*128 + (57 + r)*2;
                *reinterpret_cast<unsigned short*>(a2c + (byte ^ swz)) = 0;
            }
        }
    }
    __syncthreads();                                     // B4 (a2 ready)

    // ================= phase E (all 64 lanes) =================
    {
        const int browl = lane & 15;
        const int koff  = (lane >> 4) * 8;
        const char* a2c = (const char*)a2;
        const int swz = (browl & 7) << 4;
        union { uint4 q; bf16x8 v; } a0, a1;
        a0.q = *reinterpret_cast<const uint4*>(a2c + ((browl*128 + koff*2) ^ swz));
        a1.q = *reinterpret_cast<const uint4*>(a2c + ((browl*128 + 64 + koff*2) ^ swz));

        const uint4* bfq = (const uint4*)(cb + CB_BF);
        const int r0 = (lane >> 4) << 2;
#pragma unroll
        for (int n = 0; n < 11; ++n) {
            union { uint4 q; bf16x8 v; } bf0, bf1;
            bf0.q = bfq[(size_t)n*64 + lane];
            bf1.q = bfq[(size_t)(11 + n)*64 + lane];
            f32x4 acc = {0.f, 0.f, 0.f, 0.f};
            acc = __builtin_amdgcn_mfma_f32_16x16x32_bf16(a0.v, bf0.v, acc, 0, 0, 0);
            acc = __builtin_amdgcn_mfma_f32_16x16x32_bf16(a1.v, bf1.v, acc, 0, 0, 0);
            const int c = n*16 + (lane & 15);
#pragma unroll
            for (int r = 0; r < 4; ++r) lg[r0 + r][c] = (_Float16)acc[r];
        }
    }
    __syncthreads();                                     // B5 (lg ready)

    {
        const int host = lane & 15;
        const int tg   = lane >> 4;
        const float* cbig = cb + CB_CBIG;
#pragma unroll
        for (int i = 0; i < 4; ++i) {
            const int bll = tg + 4*i;
            const int b   = b0 + bll;
            float v[11];
#pragma unroll
            for (int jj = 0; jj < 11; ++jj)
                v[jj] = (float)lg[bll][host*11 + jj] + cbig[host*11 + jj];
            float p0 = fsig(v[0]);
            float2 av; av.x = p0; av.y = 1.f - p0;
            *reinterpret_cast<float2*>(outA + (size_t)b*32 + host*2) = av;
            float* pP = outP + (size_t)b*160 + host*10;
#pragma unroll
            for (int p = 0; p < 5; ++p) {
                float2 pv; pv.x = fsig(v[1 + 2*p]); pv.y = fsig(v[2 + 2*p]);
                *reinterpret_cast<float2*>(pP + 2*p) = pv;
            }
        }
    }
}

extern "C" void kernel_launch(void* const* d_in, const int* in_sizes, int n_in,
                              void* d_out, int out_size, void* d_ws, size_t ws_size,
                              hipStream_t stream) {
    const float* t    = (const float*)d_in[0];
    const float* h0   = (const float*)d_in[2];
    const float* Wih  = (const float*)d_in[3];
    const float* Whh  = (const float*)d_in[4];
    const float* bih  = (const float*)d_in[5];
    const float* bhh  = (const float*)d_in[6];
    const float* gatW = (const float*)d_in[7];
    const float* gal  = (const float*)d_in[8];
    const float* gar  = (const float*)d_in[9];
    const float* Win  = (const float*)d_in[10];
    const float* bin  = (const float*)d_in[11];
    const float* Wout = (const float*)d_in[12];
    const float* bout = (const float*)d_in[13];
    const float* encW = (const float*)d_in[14];
    const float* encb = (const float*)d_in[15];
    const float* aW   = (const float*)d_in[16];
    const float* ab   = (const float*)d_in[17];
    const float* pW   = (const float*)d_in[18];
    const float* pb   = (const float*)d_in[19];

    const int B = in_sizes[0] / (NW * NF);
    float* cb  = (float*)d_ws;
    float* outA = (float*)d_out;
    float* outP = (float*)d_out + (size_t)B*32;

    k_const<<<dim3(48), 256, 0, stream>>>(Win, bin, Wout, bout, gatW, gal, gar,
                                          encW, encb, aW, ab, pW, pb, cb);
    k_fused<<<dim3(B/16), 64, 0, stream>>>(t, h0, Wih, bih, gatW, Whh, bhh, cb,
                                           outA, outP, B);
}

// Round 22
// 64.568 us; speedup vs baseline: 1.0810x; 1.0810x over previous
//
#include <hip/hip_runtime.h>

#define NW 3
#define NF 48
#define NHOST 16
#define NLAT 10
#define GOUT 16
#define EDIM 19
#define PDIM 10

// const-buffer layout (floats)
#define CB_M    0     // 19x19  Wq^T Wk
#define CB_P    361   // 19x19  Wout Wv
#define CB_G    722   // 19     bq^T Wk
#define CB_H    741   // 19     Wq^T bk
#define CB_R    760   // 19     Wout bv + bout
#define CB_C0   779   // 1      bq.bk
#define CB_WAL  780   // 3      gatW @ gal
#define CB_WAR  783   // 3      gatW @ gar
#define CB_CBIG 800   // 176    folded head biases
#define CB_BF   976   // 11264 ushorts: B-frags of Wbig^T, bf16
#define CB_TOT  10240

typedef __attribute__((ext_vector_type(8))) short bf16x8;
typedef __attribute__((ext_vector_type(4))) float f32x4;

__device__ __forceinline__ float frcp(float x){ return __builtin_amdgcn_rcpf(x); }
__device__ __forceinline__ float fsig(float x){ return frcp(1.f + __expf(-x)); }
__device__ __forceinline__ float ftanh(float x){ return 1.f - 2.f*frcp(1.f + __expf(2.f*x)); }
__device__ __forceinline__ unsigned short f2bf(float x){
    union { float f; unsigned u; } v; v.f = x;
    unsigned r = v.u + 0x7FFFu + ((v.u >> 16) & 1u);
    return (unsigned short)(r >> 16);
}

// ---------------- K0: fold weights; grid-parallel ----------------
__global__ __launch_bounds__(256) void k_const(
    const float* __restrict__ Win, const float* __restrict__ bin,
    const float* __restrict__ Wout, const float* __restrict__ bout,
    const float* __restrict__ gatW, const float* __restrict__ gal,
    const float* __restrict__ gar, const float* __restrict__ encW,
    const float* __restrict__ encb,
    const float* __restrict__ aW, const float* __restrict__ ab,
    const float* __restrict__ pW, const float* __restrict__ pb,
    float* __restrict__ cb)
{
    const int w = blockIdx.x*blockDim.x + threadIdx.x;
    if (w < 786) {
        const int idx = w;
        float acc = 0.f;
        if (idx < 361) {
            int i = idx/19, j = idx%19;
            for (int e = 0; e < EDIM; ++e) acc += Win[e*EDIM+i]*Win[(EDIM+e)*EDIM+j];
        } else if (idx < 722) {
            int k = idx-361; int i = k/19, j = k%19;
            for (int e = 0; e < EDIM; ++e) acc += Wout[i*EDIM+e]*Win[(2*EDIM+e)*EDIM+j];
        } else if (idx < 741) {
            int j = idx-722;
            for (int e = 0; e < EDIM; ++e) acc += bin[e]*Win[(EDIM+e)*EDIM+j];
        } else if (idx < 760) {
            int i = idx-741;
            for (int e = 0; e < EDIM; ++e) acc += Win[e*EDIM+i]*bin[EDIM+e];
        } else if (idx < 779) {
            int i = idx-760; acc = bout[i];
            for (int e = 0; e < EDIM; ++e) acc += Wout[i*EDIM+e]*bin[2*EDIM+e];
        } else if (idx == 779) {
            for (int e = 0; e < EDIM; ++e) acc += bin[e]*bin[EDIM+e];
        } else {
            int c = idx-780; int cc = c%3; bool left = c<3;
            for (int f2 = 0; f2 < GOUT; ++f2)
                acc += gatW[cc*GOUT+f2]*(left ? gal[f2] : gar[f2]);
        }
        cb[idx] = acc;
    } else if (w < 962) {
        const int g = w - 786;
        int host = g / 11, jj = g % 11;
        float acc = (jj == 0) ? (ab[0] - ab[1]) : pb[jj-1];
        for (int l = 0; l < NLAT; ++l) {
            float coef = (jj == 0) ? (aW[l] - aW[NLAT+l]) : pW[(jj-1)*NLAT + l];
            acc += coef * encb[host*NLAT + l];
        }
        cb[CB_CBIG + g] = acc;
    } else if (w < 12226) {
        unsigned short* bf = (unsigned short*)(cb + CB_BF);
        const int u = w - 962;
        int j    = u & 7;
        int lane = (u >> 3) & 63;
        int tile = u >> 9;
        int half = tile / 11, n = tile % 11;
        int k = half*32 + ((lane >> 4) & 3)*8 + j;
        int g = n*16 + (lane & 15);
        float acc = 0.f;
        if (k < 57) {
            int host = g / 11, jj = g % 11;
            for (int l = 0; l < NLAT; ++l) {
                float coef = (jj == 0) ? (aW[l] - aW[NLAT+l]) : pW[(jj-1)*NLAT + l];
                acc += coef * encW[(host*NLAT + l)*57 + k];
            }
        }
        bf[u] = f2bf(acc);
    }
}

// ---------------- K1: fully fused F+M+E per 64-b tile (R19 best-known) ----------------
// ALL barriers at top level, executed unconditionally by all 256 threads.
// Per-thread M-state (cw, hsv, aw*) carried in registers across barriers.
__global__ __launch_bounds__(256) void k_fused(
    const float* __restrict__ t, const float* __restrict__ h0,
    const float* __restrict__ Wih, const float* __restrict__ bih,
    const float* __restrict__ gatW, const float* __restrict__ Whh,
    const float* __restrict__ bhh, const float* __restrict__ cb,
    float* __restrict__ outA, float* __restrict__ outP, int B)
{
    __shared__ __align__(16) char smraw[57344];
    __shared__ __align__(16) unsigned short a2[64][64];   // 8KB, M->E
    float (*fm)[25][64] = reinterpret_cast<float(*)[25][64]>(smraw);          // 19200B
    float* xs            = reinterpret_cast<float*>(smraw + 19200);           // 37632B
    float (*mtb)[EDIM][64] = reinterpret_cast<float(*)[EDIM][64]>(smraw + 19200);
    float (*gtb)[64]       = reinterpret_cast<float(*)[64]>(smraw + 19200 + 14592);
    float (*pcb)[EDIM][64] = reinterpret_cast<float(*)[EDIM][64]>(smraw + 19200 + 15360);
    float (*lg)[178]       = reinterpret_cast<float(*)[178]>(smraw);          // 45568B (E)

    const int tid = threadIdx.x;
    const int b0  = blockIdx.x * 64;
    const int bl  = tid & 63;
    const int sw  = tid >> 6;          // 0..3

    // ================= phase F (waves 0-2) =================
    if (tid < 192) {
        const int w = sw;
        const float* tp = t + ((size_t)(b0 + bl)*NW + w)*NF;
        float* xrow = xs + tid*49;

        const float Wal0=cb[CB_WAL],Wal1=cb[CB_WAL+1],Wal2=cb[CB_WAL+2];
        const float War0=cb[CB_WAR],War1=cb[CB_WAR+1],War2=cb[CB_WAR+2];

        float gi[9];
#pragma unroll
        for (int r = 0; r < 9; ++r) gi[r] = bih[r];
        float el[NHOST], er[NHOST];
#pragma unroll
        for (int c = 0; c < 4; ++c) {
            float xc[12];
#pragma unroll
            for (int i = 0; i < 3; ++i) {
                float4 v = *reinterpret_cast<const float4*>(tp + c*12 + i*4);
                xc[i*4+0]=v.x; xc[i*4+1]=v.y; xc[i*4+2]=v.z; xc[i*4+3]=v.w;
            }
#pragma unroll
            for (int k = 0; k < 12; ++k) xrow[c*12 + k] = xc[k];
#pragma unroll
            for (int r = 0; r < 9; ++r) {
                float a = 0.f;
#pragma unroll
                for (int k = 0; k < 12; ++k) a += xc[k]*Wih[r*NF + c*12 + k];
                gi[r] += a;
            }
#pragma unroll
            for (int u = 0; u < 4; ++u) {
                const int uu = c*4 + u;
                el[uu] = xc[u*3]*Wal0 + xc[u*3+1]*Wal1 + xc[u*3+2]*Wal2;
                er[uu] = xc[u*3]*War0 + xc[u*3+1]*War1 + xc[u*3+2]*War2;
            }
        }
#pragma unroll
        for (int r = 0; r < 9; ++r) fm[w][r][bl] = gi[r];

        float beta[NHOST];
#pragma unroll
        for (int u = 0; u < NHOST; ++u) beta[u] = 0.f;
#pragma unroll
        for (int v = 0; v < NHOST; ++v) {
            float ee[NHOST]; float sum = 0.f;
#pragma unroll
            for (int u = 0; u < NHOST; ++u) {
                float s = er[v] + el[u];
                s = fmaxf(s, 0.2f*s);
                ee[u] = __expf(s); sum += ee[u];
            }
            float inv = frcp(sum);
#pragma unroll
            for (int u = 0; u < NHOST; ++u) beta[u] += ee[u]*inv;
        }
        float g0=0.f, g1=0.f, g2=0.f;
#pragma unroll
        for (int u = 0; u < NHOST; ++u) {
            float bu = beta[u]*(1.f/16.f);
            g0 += bu*xrow[u*3+0]; g1 += bu*xrow[u*3+1]; g2 += bu*xrow[u*3+2];
        }
#pragma unroll
        for (int f2 = 0; f2 < GOUT; ++f2)
            fm[w][9+f2][bl] = g0*gatW[f2] + g1*gatW[GOUT+f2] + g2*gatW[2*GOUT+f2];
    }
    __syncthreads();                                     // B1 (all threads)

    // ================= phase M (waves 0-2, s = sw) =================
    float cw[EDIM];
    float hsv = 0.f, aw0 = 0.f, aw1 = 0.f, aw2 = 0.f;
#pragma unroll
    for (int i = 0; i < EDIM; ++i) cw[i] = 0.f;

    if (tid < 192) {
        const int s = sw;
        const int b = b0 + bl;
        float h[3] = { h0[(size_t)b*3+0], h0[(size_t)b*3+1], h0[(size_t)b*3+2] };
        float ch[NW][3];
#pragma unroll
        for (int w = 0; w < NW; ++w) {
            float gi[9];
#pragma unroll
            for (int r = 0; r < 9; ++r) gi[r] = fm[w][r][bl];
            float gh[9];
#pragma unroll
            for (int r = 0; r < 9; ++r)
                gh[r] = bhh[r] + h[0]*Whh[r*3+0] + h[1]*Whh[r*3+1] + h[2]*Whh[r*3+2];
#pragma unroll
            for (int j = 0; j < 3; ++j) {
                float rg = fsig(gi[j]   + gh[j]);
                float zg = fsig(gi[3+j] + gh[3+j]);
                float ng = ftanh(gi[6+j] + rg*gh[6+j]);
                h[j] = (1.f - zg)*ng + zg*h[j];
            }
            ch[w][0]=h[0]; ch[w][1]=h[1]; ch[w][2]=h[2];
        }
#pragma unroll
        for (int j = 0; j < 3; ++j)
            cw[j] = (s==0) ? ch[0][j] : (s==1) ? ch[1][j] : ch[2][j];
#pragma unroll
        for (int f2 = 0; f2 < GOUT; ++f2)
            cw[3+f2] = fm[s][9+f2][bl];

        float gt = 0.f;
#pragma unroll
        for (int i = 0; i < EDIM; ++i) { hsv += cw[i]*cb[CB_H+i]; gt += cw[i]*cb[CB_G+i]; }
#pragma unroll
        for (int i = 0; i < EDIM; ++i) {
            float a = 0.f;
#pragma unroll
            for (int j = 0; j < EDIM; ++j) a += cb[CB_M+i*EDIM+j]*cw[j];
            mtb[s][i][bl] = a;
        }
        gtb[s][bl] = gt;
    }
    __syncthreads();                                     // B2 (all threads)

    if (tid < 192) {
        const int s = sw;
        const float c0 = cb[CB_C0];
        float sc[NW];
#pragma unroll
        for (int tt = 0; tt < NW; ++tt) {
            float a = 0.f;
#pragma unroll
            for (int i = 0; i < EDIM; ++i) a += cw[i]*mtb[tt][i][bl];
            sc[tt] = (a + gtb[tt][bl] + hsv + c0) * 0.2294157338705618f;
        }
        float m = fmaxf(sc[0], fmaxf(sc[1], sc[2]));
        float e0=__expf(sc[0]-m), e1=__expf(sc[1]-m), e2=__expf(sc[2]-m);
        float inv = frcp(e0+e1+e2);
        aw0=e0*inv; aw1=e1*inv; aw2=e2*inv;

#pragma unroll
        for (int i = 0; i < EDIM; ++i) {
            float a = 0.f;
#pragma unroll
            for (int j = 0; j < EDIM; ++j) a += cb[CB_P+i*EDIM+j]*cw[j];
            pcb[s][i][bl] = a;
        }
    }
    __syncthreads();                                     // B3 (all threads)

    if (tid < 192) {
        const int s = sw;
        char* a2c = (char*)a2;
        const int swz = (bl & 7) << 4;
#pragma unroll
        for (int i = 0; i < EDIM; ++i) {
            float v = cb[CB_R+i] + aw0*pcb[0][i][bl] + aw1*pcb[1][i][bl]
                    + aw2*pcb[2][i][bl];
            const int byte = bl*128 + (s*EDIM + i)*2;
            *reinterpret_cast<unsigned short*>(a2c + (byte ^ swz)) = f2bf(v);
        }
        if (s == 0) {
#pragma unroll
            for (int r = 0; r < 7; ++r) {
                const int byte = bl*128 + (57 + r)*2;
                *reinterpret_cast<unsigned short*>(a2c + (byte ^ swz)) = 0;
            }
        }
    }
    __syncthreads();                                     // B4 (all threads)

    // ================= phase E (all 256 threads) =================
    const int lane = tid & 63;
    const int wv   = __builtin_amdgcn_readfirstlane(sw);
    {
        const int browl = wv*16 + (lane & 15);
        const int koff  = (lane >> 4) * 8;
        const char* a2c = (const char*)a2;
        const int swz = (browl & 7) << 4;
        union { uint4 q; bf16x8 v; } a0, a1;
        a0.q = *reinterpret_cast<const uint4*>(a2c + ((browl*128 + koff*2) ^ swz));
        a1.q = *reinterpret_cast<const uint4*>(a2c + ((browl*128 + 64 + koff*2) ^ swz));

        const uint4* bfq = (const uint4*)(cb + CB_BF);
        const int r0 = wv*16 + ((lane >> 4) << 2);
#pragma unroll
        for (int n = 0; n < 11; ++n) {
            union { uint4 q; bf16x8 v; } bf0, bf1;
            bf0.q = bfq[(size_t)n*64 + lane];
            bf1.q = bfq[(size_t)(11 + n)*64 + lane];
            f32x4 acc = {0.f, 0.f, 0.f, 0.f};
            acc = __builtin_amdgcn_mfma_f32_16x16x32_bf16(a0.v, bf0.v, acc, 0, 0, 0);
            acc = __builtin_amdgcn_mfma_f32_16x16x32_bf16(a1.v, bf1.v, acc, 0, 0, 0);
            const int c = n*16 + (lane & 15);
#pragma unroll
            for (int r = 0; r < 4; ++r) lg[r0 + r][c] = acc[r];
        }
    }
    __syncthreads();                                     // B5 (all threads)

    {
        const int host = tid & 15;
        const int tg   = tid >> 4;
        const float* cbig = cb + CB_CBIG;
#pragma unroll
        for (int i = 0; i < 4; ++i) {
            const int bll = tg + 16*i;
            const int b   = b0 + bll;
            float v[11];
#pragma unroll
            for (int jj = 0; jj < 11; ++jj)
                v[jj] = lg[bll][host*11 + jj] + cbig[host*11 + jj];
            float p0 = fsig(v[0]);
            float2 av; av.x = p0; av.y = 1.f - p0;
            *reinterpret_cast<float2*>(outA + (size_t)b*32 + host*2) = av;
            float* pP = outP + (size_t)b*160 + host*10;
#pragma unroll
            for (int p = 0; p < 5; ++p) {
                float2 pv; pv.x = fsig(v[1 + 2*p]); pv.y = fsig(v[2 + 2*p]);
                *reinterpret_cast<float2*>(pP + 2*p) = pv;
            }
        }
    }
}

extern "C" void kernel_launch(void* const* d_in, const int* in_sizes, int n_in,
                              void* d_out, int out_size, void* d_ws, size_t ws_size,
                              hipStream_t stream) {
    const float* t    = (const float*)d_in[0];
    const float* h0   = (const float*)d_in[2];
    const float* Wih  = (const float*)d_in[3];
    const float* Whh  = (const float*)d_in[4];
    const float* bih  = (const float*)d_in[5];
    const float* bhh  = (const float*)d_in[6];
    const float* gatW = (const float*)d_in[7];
    const float* gal  = (const float*)d_in[8];
    const float* gar  = (const float*)d_in[9];
    const float* Win  = (const float*)d_in[10];
    const float* bin  = (const float*)d_in[11];
    const float* Wout = (const float*)d_in[12];
    const float* bout = (const float*)d_in[13];
    const float* encW = (const float*)d_in[14];
    const float* encb = (const float*)d_in[15];
    const float* aW   = (const float*)d_in[16];
    const float* ab   = (const float*)d_in[17];
    const float* pW   = (const float*)d_in[18];
    const float* pb   = (const float*)d_in[19];

    const int B = in_sizes[0] / (NW * NF);
    float* cb  = (float*)d_ws;
    float* outA = (float*)d_out;
    float* outP = (float*)d_out + (size_t)B*32;

    k_const<<<dim3(48), 256, 0, stream>>>(Win, bin, Wout, bout, gatW, gal, gar,
                                          encW, encb, aW, ab, pW, pb, cb);
    k_fused<<<dim3(B/64), 256, 0, stream>>>(t, h0, Wih, bih, gatW, Whh, bhh, cb,
                                            outA, outP, B);
}